// Round 1
// baseline (731.730 us; speedup 1.0000x reference)
//
#include <hip/hip_runtime.h>
#include <math.h>

#define BB 32
#define DD 1024
#define SS 4096
#define VVOUT 32003
#define NCHUNK 32
#define ROWS_PER_CHUNK (SS / NCHUNK)   // 128
#define PART_STRIDE 1032               // floats per partial record (M, L, pad, U[1024])

// Y[i] = bias[i % N]  (broadcast bias over M rows)
__global__ void fill_bias(float* __restrict__ Y, const float* __restrict__ bias,
                          int N, int total) {
  int i = blockIdx.x * 256 + threadIdx.x;
  if (i < total) Y[i] = bias[i - (i / N) * N];
}

// embs[m][d] = emb[tokens[m]][d]
__global__ void gather_emb(const int* __restrict__ tokens, const float* __restrict__ emb,
                           float* __restrict__ embs) {
  int i = blockIdx.x * 256 + threadIdx.x;   // 32*1024 total
  int m = i >> 10, d = i & 1023;
  embs[i] = emb[(size_t)tokens[m] * DD + d];
}

// Y[m][n] += sum_{k in chunk} X[m][k] * W[n*ldw + k]   (M=32 fixed)
// One wave per 64 rows of W; lane owns row n; X rows are wave-uniform -> scalar loads.
__global__ __launch_bounds__(64) void matmul_nt(
    float* __restrict__ Y, const float* __restrict__ X, const float* __restrict__ W,
    int N, int K, int ldw, int xld, int ksplit) {
  int n = blockIdx.x * 64 + threadIdx.x;
  int nn = n < N ? n : N - 1;
  int kchunk = K / ksplit;
  int k0 = blockIdx.y * kchunk;
  const float4* wp = (const float4*)(W + (size_t)nn * ldw + k0);
  float acc[BB];
#pragma unroll
  for (int m = 0; m < BB; m++) acc[m] = 0.f;
  for (int kk = 0; kk < kchunk; kk += 4) {
    float4 w4 = wp[kk >> 2];
#pragma unroll
    for (int m = 0; m < BB; m++) {
      float4 x4 = *(const float4*)(X + (size_t)m * xld + k0 + kk);
      acc[m] = fmaf(w4.x, x4.x, fmaf(w4.y, x4.y, fmaf(w4.z, x4.z, fmaf(w4.w, x4.w, acc[m]))));
    }
  }
  if (n < N) {
#pragma unroll
    for (int m = 0; m < BB; m++) atomicAdd(&Y[(size_t)m * N + n], acc[m]);
  }
}

// h[m][d] from gi (already = X@Wih.T + bih) and bhh (gh = bhh since h_prev = 0)
__global__ void gru_act(const float* __restrict__ gi, const float* __restrict__ bhh,
                        float* __restrict__ h, int total) {
  int i = blockIdx.x * 256 + threadIdx.x;   // 32*1024
  if (i >= total) return;
  int m = i >> 10, d = i & 1023;
  const float* g = gi + (size_t)m * 3072;
  float ir = g[d], iz = g[d + 1024], inn = g[d + 2048];
  float hr = bhh[d], hz = bhh[d + 1024], hn = bhh[d + 2048];
  float r = 1.f / (1.f + expf(-(ir + hr)));
  float z = 1.f / (1.f + expf(-(iz + hz)));
  float nv = tanhf(inn + r * hn);
  h[i] = (1.f - z) * nv;   // + z*h_prev, h_prev = 0
}

// One enc pass: per (b, s-chunk) compute online-softmax partial {M, L, U[1024]}
__global__ __launch_bounds__(256) void attn_partial(
    const float* __restrict__ ht, const float* __restrict__ enc,
    const int* __restrict__ mask, float* __restrict__ part) {
  int b = blockIdx.x;
  int chunk = blockIdx.y;
  int w = threadIdx.x >> 6;
  int l = threadIdx.x & 63;
  const float* encb = enc + (size_t)b * SS * DD;
  const float* htb = ht + (size_t)b * DD;

  float4 h4[4];
#pragma unroll
  for (int j = 0; j < 4; j++) h4[j] = *(const float4*)(htb + 256 * j + 4 * l);

  float4 acc[4];
#pragma unroll
  for (int j = 0; j < 4; j++) acc[j] = make_float4(0.f, 0.f, 0.f, 0.f);
  float mw = -INFINITY, lw = 0.f;

  int s0 = chunk * ROWS_PER_CHUNK;
  for (int i = 0; i < ROWS_PER_CHUNK / 4; i++) {
    int s = s0 + 4 * i + w;             // each wave owns its own rows
    if (mask[(size_t)b * SS + s] != 0) {
      const float* er = encb + (size_t)s * DD;
      float4 e[4];
#pragma unroll
      for (int j = 0; j < 4; j++) e[j] = *(const float4*)(er + 256 * j + 4 * l);
      float p = 0.f;
#pragma unroll
      for (int j = 0; j < 4; j++)
        p += e[j].x * h4[j].x + e[j].y * h4[j].y + e[j].z * h4[j].z + e[j].w * h4[j].w;
#pragma unroll
      for (int off = 32; off; off >>= 1) p += __shfl_xor(p, off, 64);
      float mn = fmaxf(mw, p);
      float sc = expf(mw - mn);         // expf(-inf)=0 on first row
      float al = expf(p - mn);
      lw = lw * sc + al;
#pragma unroll
      for (int j = 0; j < 4; j++) {
        acc[j].x = acc[j].x * sc + al * e[j].x;
        acc[j].y = acc[j].y * sc + al * e[j].y;
        acc[j].z = acc[j].z * sc + al * e[j].z;
        acc[j].w = acc[j].w * sc + al * e[j].w;
      }
      mw = mn;
    }
  }

  __shared__ float sml[4][2];
  __shared__ float sacc[4][1024];
  if (l == 0) { sml[w][0] = mw; sml[w][1] = lw; }
#pragma unroll
  for (int j = 0; j < 4; j++) *(float4*)&sacc[w][256 * j + 4 * l] = acc[j];
  __syncthreads();

  float M = fmaxf(fmaxf(sml[0][0], sml[1][0]), fmaxf(sml[2][0], sml[3][0]));
  float L = 0.f;
  float scw[4];
#pragma unroll
  for (int ww = 0; ww < 4; ww++) {
    float mm = sml[ww][0];
    float s_ = (mm == -INFINITY) ? 0.f : expf(mm - M);
    scw[ww] = s_;
    L += sml[ww][1] * s_;
  }
  float* P = part + (size_t)(b * NCHUNK + chunk) * PART_STRIDE;
  int tid = threadIdx.x;
  if (tid == 0) { P[0] = M; P[1] = L; }
  float4 u = make_float4(0.f, 0.f, 0.f, 0.f);
#pragma unroll
  for (int ww = 0; ww < 4; ww++) {
    float4 a = *(const float4*)&sacc[ww][4 * tid];
    u.x += scw[ww] * a.x; u.y += scw[ww] * a.y;
    u.z += scw[ww] * a.z; u.w += scw[ww] * a.w;
  }
  *(float4*)&P[8 + 4 * tid] = u;
}

// Combine 32 partials per b -> summary; also build xcat = [h_t | summary]
__global__ __launch_bounds__(256) void attn_reduce(
    const float* __restrict__ part, const float* __restrict__ ht,
    float* __restrict__ xcat) {
  int b = blockIdx.x;
  int tid = threadIdx.x;
  const float* Pb = part + (size_t)b * NCHUNK * PART_STRIDE;
  float M = -INFINITY;
#pragma unroll
  for (int c = 0; c < NCHUNK; c++) M = fmaxf(M, Pb[c * PART_STRIDE]);
  float L = 0.f;
  float sc[NCHUNK];
#pragma unroll
  for (int c = 0; c < NCHUNK; c++) {
    float mc = Pb[c * PART_STRIDE];
    float s_ = (mc == -INFINITY) ? 0.f : expf(mc - M);
    sc[c] = s_;
    L += Pb[c * PART_STRIDE + 1] * s_;
  }
  float inv = (L > 0.f) ? 1.f / L : 0.f;
  float4 u = make_float4(0.f, 0.f, 0.f, 0.f);
#pragma unroll
  for (int c = 0; c < NCHUNK; c++) {
    float4 a = *(const float4*)&Pb[c * PART_STRIDE + 8 + 4 * tid];
    u.x += sc[c] * a.x; u.y += sc[c] * a.y;
    u.z += sc[c] * a.z; u.w += sc[c] * a.w;
  }
  u.x *= inv; u.y *= inv; u.z *= inv; u.w *= inv;
  *(float4*)&xcat[(size_t)b * 2048 + 1024 + 4 * tid] = u;
  *(float4*)&xcat[(size_t)b * 2048 + 4 * tid] = *(const float4*)&ht[(size_t)b * DD + 4 * tid];
}

extern "C" void kernel_launch(void* const* d_in, const int* in_sizes, int n_in,
                              void* d_out, int out_size, void* d_ws, size_t ws_size,
                              hipStream_t stream) {
  const int*   tokens  = (const int*)d_in[0];
  const float* enc     = (const float*)d_in[1];
  const int*   encmask = (const int*)d_in[2];
  const float* emb     = (const float*)d_in[3];
  const float* Wih0    = (const float*)d_in[4];
  // d_in[5] = Whh0 unused (h0 == 0)
  const float* bih0    = (const float*)d_in[6];
  const float* bhh0    = (const float*)d_in[7];
  const float* Wih1    = (const float*)d_in[8];
  // d_in[9] = Whh1 unused (h0 == 0)
  const float* bih1    = (const float*)d_in[10];
  const float* bhh1    = (const float*)d_in[11];
  const float* preoutW = (const float*)d_in[12];
  const float* preoutb = (const float*)d_in[13];
  const float* outW    = (const float*)d_in[14];
  const float* outb    = (const float*)d_in[15];
  float* out = (float*)d_out;
  float* ws  = (float*)d_ws;

  float* embs = ws;                       // 32*1024
  float* gi0  = embs + 32 * 1024;         // 32*3072
  float* h    = gi0 + 32 * 3072;          // 32*1024
  float* gi1  = h + 32 * 1024;            // 32*3072
  float* ht   = gi1 + 32 * 3072;          // 32*1024
  float* part = ht + 32 * 1024;           // 32*32*1032
  float* xcat = part + 32 * 32 * PART_STRIDE; // 32*2048
  float* opre = xcat + 32 * 2048;         // 32*1024

  gather_emb<<<128, 256, 0, stream>>>(tokens, emb, embs);

  fill_bias<<<(32 * 3072 + 255) / 256, 256, 0, stream>>>(gi0, bih0, 3072, 32 * 3072);
  matmul_nt<<<dim3(48, 4), 64, 0, stream>>>(gi0, embs, Wih0, 3072, 1024, 2048, 1024, 4);
  gru_act<<<128, 256, 0, stream>>>(gi0, bhh0, h, 32 * 1024);

  fill_bias<<<(32 * 3072 + 255) / 256, 256, 0, stream>>>(gi1, bih1, 3072, 32 * 3072);
  matmul_nt<<<dim3(48, 4), 64, 0, stream>>>(gi1, h, Wih1, 3072, 1024, 1024, 1024, 4);
  gru_act<<<128, 256, 0, stream>>>(gi1, bhh1, ht, 32 * 1024);

  attn_partial<<<dim3(BB, NCHUNK), 256, 0, stream>>>(ht, enc, encmask, part);
  attn_reduce<<<BB, 256, 0, stream>>>(part, ht, xcat);

  fill_bias<<<(32 * 1024 + 255) / 256, 256, 0, stream>>>(opre, preoutb, 1024, 32 * 1024);
  matmul_nt<<<dim3(16, 4), 64, 0, stream>>>(opre, xcat, preoutW, 1024, 2048, 2048, 2048, 4);

  fill_bias<<<(32 * VVOUT + 255) / 256, 256, 0, stream>>>(out, outb, VVOUT, 32 * VVOUT);
  matmul_nt<<<dim3((VVOUT + 63) / 64, 2), 64, 0, stream>>>(out, opre, outW, VVOUT, 1024, 1024, 1024, 2);
}